// Round 1
// baseline (487.001 us; speedup 1.0000x reference)
//
#include <hip/hip_runtime.h>

// PointPillarScatter3d: scatter-mean of pillar features into BEV grid.
// inputs: d_in[0] = pillar_features [N, C] fp32, d_in[1] = voxel_coords [N, 4] int32 (b,z,y,x)
// output: bev [B, C*NZ, NY, NX] fp32, where bev[b][c][y][x] = mean over points in cell.

constexpr int NXc = 360;
constexpr int NYc = 360;
constexpr int NZc = 1;
constexpr int Cc  = 128;
constexpr int Bc  = 4;
constexpr int Sc  = NZc * NYc * NXc;  // 129600 cells per sample

// Phase 1: per-cell point counts (int atomics; only 160K of them)
__global__ void pps_count_kernel(const int* __restrict__ coords,
                                 int* __restrict__ cnt, int N) {
    int i = blockIdx.x * blockDim.x + threadIdx.x;
    if (i >= N) return;
    int4 c = reinterpret_cast<const int4*>(coords)[i];  // (b, z, y, x)
    int gidx = c.x * Sc + c.y * (NYc * NXc) + c.z * NXc + c.w;
    atomicAdd(&cnt[gidx], 1);
}

// Phase 2: scatter with division folded in (mean = sum(v/cnt)).
// 32 threads per point, each handles 4 channels via float4 (coalesced feature read).
// Output address stride between channels is S (scattered writes - unavoidable in
// this layout without a transpose stage; that's the next optimization).
__global__ void pps_scatter_kernel(const float* __restrict__ feat,
                                   const int* __restrict__ coords,
                                   const int* __restrict__ cnt,
                                   float* __restrict__ out, int N) {
    int t = blockIdx.x * blockDim.x + threadIdx.x;
    int i = t >> 5;        // point index
    int g = t & 31;        // channel group (4 channels each)
    if (i >= N) return;

    int4 c = reinterpret_cast<const int4*>(coords)[i];  // (b, z, y, x)
    int s    = c.y * (NYc * NXc) + c.z * NXc + c.w;     // spatial index in sample
    int gidx = c.x * Sc + s;

    int n = cnt[gidx];     // >= 1 (this point counted itself)
    float4 v = reinterpret_cast<const float4*>(feat + (size_t)i * Cc)[g];

    // out flat layout: b*(C*S) + c*S + s
    float* base = out + ((size_t)c.x * Cc + (size_t)g * 4) * Sc + s;

    if (n == 1) {
        // sole writer for this cell: plain stores (inv == 1)
        base[0 * (size_t)Sc] = v.x;
        base[1 * (size_t)Sc] = v.y;
        base[2 * (size_t)Sc] = v.z;
        base[3 * (size_t)Sc] = v.w;
    } else {
        float inv = 1.0f / (float)n;
        atomicAdd(&base[0 * (size_t)Sc], v.x * inv);
        atomicAdd(&base[1 * (size_t)Sc], v.y * inv);
        atomicAdd(&base[2 * (size_t)Sc], v.z * inv);
        atomicAdd(&base[3 * (size_t)Sc], v.w * inv);
    }
}

extern "C" void kernel_launch(void* const* d_in, const int* in_sizes, int n_in,
                              void* d_out, int out_size, void* d_ws, size_t ws_size,
                              hipStream_t stream) {
    const float* feat   = reinterpret_cast<const float*>(d_in[0]);
    const int*   coords = reinterpret_cast<const int*>(d_in[1]);
    float*       out    = reinterpret_cast<float*>(d_out);
    int*         cnt    = reinterpret_cast<int*>(d_ws);  // B*S ints = 2.07 MB

    const int N = in_sizes[0] / Cc;  // 160000

    // Zero output (harness poisons with 0xAA; we accumulate into it) and counts.
    hipMemsetAsync(d_out, 0, (size_t)out_size * sizeof(float), stream);
    hipMemsetAsync(d_ws, 0, (size_t)Bc * Sc * sizeof(int), stream);

    {
        int threads = 256;
        int blocks = (N + threads - 1) / threads;
        pps_count_kernel<<<blocks, threads, 0, stream>>>(coords, cnt, N);
    }
    {
        int threads = 256;
        long long total = (long long)N * 32;
        int blocks = (int)((total + threads - 1) / threads);
        pps_scatter_kernel<<<blocks, threads, 0, stream>>>(feat, coords, cnt, out, N);
    }
}

// Round 2
// 164.361 us; speedup vs baseline: 2.9630x; 2.9630x over previous
//
#include <hip/hip_runtime.h>

// PointPillarScatter3d: scatter-mean of pillar features into BEV grid.
// Gather formulation: bucket points per cell, then one coalesced output pass.
// inputs: d_in[0] = pillar_features [N, C] fp32, d_in[1] = voxel_coords [N,4] int32 (b,z,y,x)
// output: bev [B, C, NY, NX] fp32.

constexpr int NXc = 360;
constexpr int NYc = 360;
constexpr int NZc = 1;
constexpr int Cc  = 128;
constexpr int Bc  = 4;
constexpr int Sc  = NZc * NYc * NXc;   // 129600 cells per sample
constexpr int BSc = Bc * Sc;           // 518400 total cells
constexpr int CAP  = 16;               // max tracked points/cell (P[overflow] ~ 1e-16 at lambda=0.31)
constexpr int TILE = 64;               // cells per block in gather

// ---- Gather path ------------------------------------------------------------

// One pass: count points per cell and record point index in slot-major buckets.
__global__ void pps_fill_kernel(const int* __restrict__ coords,
                                int* __restrict__ cnt,
                                int* __restrict__ bucket, int N) {
    int i = blockIdx.x * blockDim.x + threadIdx.x;
    if (i >= N) return;
    int4 c = reinterpret_cast<const int4*>(coords)[i];       // (b, z, y, x)
    int gidx = c.x * Sc + c.y * (NYc * NXc) + c.z * NXc + c.w;
    int slot = atomicAdd(&cnt[gidx], 1);
    if (slot < CAP) bucket[(size_t)slot * BSc + gidx] = i;   // slot-major: coalesced reads later
}

// Each block: 64 consecutive cells x all 128 channels. Output written once,
// coalesced (lanes vary s). Empty cells produce 0 -> no output memset needed.
__global__ __launch_bounds__(256)
void pps_gather_kernel(const float* __restrict__ feat,
                       const int* __restrict__ cnt,
                       const int* __restrict__ bucket,
                       float* __restrict__ out) {
    const int tile = blockIdx.x;                  // 0 .. B*S/TILE - 1
    const int b    = tile / (Sc / TILE);
    const int s0   = (tile % (Sc / TILE)) * TILE;
    const int t    = threadIdx.x;
    const int s_off = t & (TILE - 1);
    const int c0    = t >> 6;                     // 0..3 -> channel quarter

    __shared__ int scnt[TILE];
    __shared__ int sidx[CAP][TILE];

    const int gbase = b * Sc + s0;
    if (t < TILE) {
        int n = cnt[gbase + t];
        scnt[t] = n;
        int m = n < CAP ? n : CAP;
        for (int k = 0; k < m; ++k)
            sidx[k][t] = bucket[(size_t)k * BSc + gbase + t];
    }
    __syncthreads();

    const int n = scnt[s_off];
    const int m = n < CAP ? n : CAP;
    const float inv = n > 0 ? 1.0f / (float)n : 0.0f;

    float* obase = out + (size_t)b * Cc * Sc + s0 + s_off;
    #pragma unroll 4
    for (int kc = 0; kc < 32; ++kc) {
        const int c = c0 * 32 + kc;               // each quarter covers contiguous channels
        float acc = 0.0f;
        for (int j = 0; j < m; ++j) {
            int p = sidx[j][s_off];
            acc += feat[(size_t)p * Cc + c];
        }
        obase[(size_t)c * Sc] = acc * inv;
    }
}

// ---- Fallback path (round-1 atomic scatter; used only if ws too small) ------

__global__ void pps_count_kernel(const int* __restrict__ coords,
                                 int* __restrict__ cnt, int N) {
    int i = blockIdx.x * blockDim.x + threadIdx.x;
    if (i >= N) return;
    int4 c = reinterpret_cast<const int4*>(coords)[i];
    int gidx = c.x * Sc + c.y * (NYc * NXc) + c.z * NXc + c.w;
    atomicAdd(&cnt[gidx], 1);
}

__global__ void pps_scatter_kernel(const float* __restrict__ feat,
                                   const int* __restrict__ coords,
                                   const int* __restrict__ cnt,
                                   float* __restrict__ out, int N) {
    int t = blockIdx.x * blockDim.x + threadIdx.x;
    int i = t >> 5;
    int g = t & 31;
    if (i >= N) return;
    int4 c = reinterpret_cast<const int4*>(coords)[i];
    int s    = c.y * (NYc * NXc) + c.z * NXc + c.w;
    int gidx = c.x * Sc + s;
    int n = cnt[gidx];
    float4 v = reinterpret_cast<const float4*>(feat + (size_t)i * Cc)[g];
    float* base = out + ((size_t)c.x * Cc + (size_t)g * 4) * Sc + s;
    if (n == 1) {
        base[0 * (size_t)Sc] = v.x;
        base[1 * (size_t)Sc] = v.y;
        base[2 * (size_t)Sc] = v.z;
        base[3 * (size_t)Sc] = v.w;
    } else {
        float inv = 1.0f / (float)n;
        atomicAdd(&base[0 * (size_t)Sc], v.x * inv);
        atomicAdd(&base[1 * (size_t)Sc], v.y * inv);
        atomicAdd(&base[2 * (size_t)Sc], v.z * inv);
        atomicAdd(&base[3 * (size_t)Sc], v.w * inv);
    }
}

// ---- Launch -----------------------------------------------------------------

extern "C" void kernel_launch(void* const* d_in, const int* in_sizes, int n_in,
                              void* d_out, int out_size, void* d_ws, size_t ws_size,
                              hipStream_t stream) {
    const float* feat   = reinterpret_cast<const float*>(d_in[0]);
    const int*   coords = reinterpret_cast<const int*>(d_in[1]);
    float*       out    = reinterpret_cast<float*>(d_out);
    int*         cnt    = reinterpret_cast<int*>(d_ws);

    const int N = in_sizes[0] / Cc;  // 160000

    const size_t cnt_bytes    = (size_t)BSc * sizeof(int);            // 2.07 MB
    const size_t bucket_bytes = (size_t)CAP * BSc * sizeof(int);      // 33.2 MB

    if (ws_size >= cnt_bytes + bucket_bytes) {
        // Gather path
        int* bucket = reinterpret_cast<int*>((char*)d_ws + cnt_bytes);
        hipMemsetAsync(d_ws, 0, cnt_bytes, stream);
        {
            int threads = 256;
            int blocks = (N + threads - 1) / threads;
            pps_fill_kernel<<<blocks, threads, 0, stream>>>(coords, cnt, bucket, N);
        }
        {
            int blocks = BSc / TILE;  // 8100
            pps_gather_kernel<<<blocks, 256, 0, stream>>>(feat, cnt, bucket, out);
        }
    } else {
        // Fallback: atomic scatter (round-1 path)
        hipMemsetAsync(d_out, 0, (size_t)out_size * sizeof(float), stream);
        hipMemsetAsync(d_ws, 0, cnt_bytes, stream);
        {
            int threads = 256;
            int blocks = (N + threads - 1) / threads;
            pps_count_kernel<<<blocks, threads, 0, stream>>>(coords, cnt, N);
        }
        {
            int threads = 256;
            long long total = (long long)N * 32;
            int blocks = (int)((total + threads - 1) / threads);
            pps_scatter_kernel<<<blocks, threads, 0, stream>>>(feat, coords, cnt, out, N);
        }
    }
}